// Round 18
// baseline (52.296 us; speedup 1.0000x reference)
//
#include <hip/hip_runtime.h>
#include <math.h>

// ---------------------------------------------------------------------------
// AttentiveFPModule: knn(K=3) attentive interpolate + concat + Linear + BN + LeakyReLU
// Sizes: Nx=4096, Ny=16384, C=256, Cs=128, Co=256, B=4, Kin=384
// 4 launches:
//   k_main : [0,1024) knn scan + fused attv+gather -> Abuf A-fragments
//            [1024,1072) W1 -> Bbuf fragments; [1072,1136) tail outputs
//   k_gemm : MFMA; B-half (96KB) staged in LDS once; A prefetched to regs.
//            h stored BF16 in ws (stats computed from f32 accs pre-rounding).
//   k_stats: reduce per-block partials -> BN scale/shift (1 block)
//   k_final: read bf16 h -> BN apply + LeakyReLU -> f32 out (single write)
// Lessons: R16 B-LDS staging -21us (B-L2-bound). R10 fence +29us. R11/R15
//   occupancy raises regressed. R18: h f32->bf16 intermediate: -16.8MB HBM.
// ---------------------------------------------------------------------------

#define KNEI 3
#define GL 16           // lanes per y-point in k_main knn
#define UNR 4           // scan unroll
#define KCAP 1280       // staged segment capacity (float4s)
#define CIN 256         // C
#define CSK 128         // Cs
#define CO  256         // Co
#define NKS 12          // Kin / 32
#define NNT 16          // Co / 16
#define NYF 16384.0f
#define NPOS4 12288     // Ny*3/4
#define NTAIL4 16384    // NPOS4 + Ny/4

typedef __attribute__((ext_vector_type(8))) short bf16x8;
typedef __attribute__((ext_vector_type(4))) float f32x4;

__device__ __forceinline__ ushort f2bf(float f) {
    unsigned u = __float_as_uint(f);
    u += 0x7fffu + ((u >> 16) & 1u);
    return (ushort)(u >> 16);
}

__device__ __forceinline__ float bf2f(ushort u) {
    return __uint_as_float(((unsigned)u) << 16);
}

__device__ __forceinline__ bool nless(float da, int ia, float db, int ib) {
    return (da < db) || (da == db && ia < ib);
}

__device__ __forceinline__ void ins3f(float dd, int j,
                                      float& d0, int& i0,
                                      float& d1, int& i1,
                                      float& d2, int& i2) {
    bool l0 = dd < d0;
    bool l1 = dd < d1;
    bool l2 = dd < d2;
    float n2 = l1 ? d1 : (l2 ? dd : d2); int m2 = l1 ? i1 : (l2 ? j : i2);
    float n1 = l0 ? d0 : (l1 ? dd : d1); int m1 = l0 ? i0 : (l1 ? j : i1);
    float n0 = l0 ? dd : d0;             int m0 = l0 ? j  : i0;
    d0 = n0; i0 = m0; d1 = n1; i1 = m1; d2 = n2; i2 = m2;
}

__device__ __forceinline__ void ins3t(float dd, int j,
                                      float& d0, int& i0,
                                      float& d1, int& i1,
                                      float& d2, int& i2) {
    bool l0 = nless(dd, j, d0, i0);
    bool l1 = nless(dd, j, d1, i1);
    bool l2 = nless(dd, j, d2, i2);
    float n2 = l1 ? d1 : (l2 ? dd : d2); int m2 = l1 ? i1 : (l2 ? j : i2);
    float n1 = l0 ? d0 : (l1 ? dd : d1); int m1 = l0 ? i0 : (l1 ? j : i1);
    float n0 = l0 ? dd : d0;             int m0 = l0 ? j  : i0;
    d0 = n0; i0 = m0; d1 = n1; i1 = m1; d2 = n2; i2 = m2;
}

// K1 (multi-role by block range):
//   [0, Ny/16)              : knn + fused attv/gather -> Abuf
//   [Ny/16, Ny/16+48)       : W1 -> Bbuf MFMA B-fragments (bf16)
//   [Ny/16+48, Ny/16+48+64) : tail outputs
__global__ __launch_bounds__(256) void k_main(
                      const float* __restrict__ pos,
                      const int* __restrict__ batch,
                      const float* __restrict__ pos_skip,
                      const int* __restrict__ batch_skip,
                      const float* __restrict__ x,
                      const float* __restrict__ x_skip,
                      const float* __restrict__ w_att,
                      const float* __restrict__ W1,
                      uint4* __restrict__ Abuf, uint4* __restrict__ Bbuf,
                      const float4* __restrict__ pos_skip4,
                      const int4* __restrict__ batch4,
                      float4* __restrict__ out_tail4,
                      int Nx, int Ny, int NB) {
    __shared__ float4 seg[KCAP + 48];
    __shared__ int   startL[12];
    __shared__ int   idxL[16][3];
    __shared__ float wL[16][3];
    __shared__ float coefL[16][3];
    __shared__ float attP[3][16][16];
    const int bid = blockIdx.x;
    const int nkb = Ny >> 4;             // 1024
    const int tid = threadIdx.x;

    if (bid >= nkb) {
        if (bid < nkb + 48) {
            int wave = tid >> 6, lane = tid & 63;
            int p  = (bid - nkb) * 4 + wave;   // 0..191
            int ks = p >> 4, nt = p & 15;
            int kb = ks * 32 + (lane >> 4) * 8;
            int n  = nt * 16 + (lane & 15);
            ushort u[8];
            #pragma unroll
            for (int j = 0; j < 8; ++j)
                u[j] = f2bf(W1[(size_t)(kb + j) * CO + n]);
            uint4 o;
            o.x = (unsigned)u[0] | ((unsigned)u[1] << 16);
            o.y = (unsigned)u[2] | ((unsigned)u[3] << 16);
            o.z = (unsigned)u[4] | ((unsigned)u[5] << 16);
            o.w = (unsigned)u[6] | ((unsigned)u[7] << 16);
            Bbuf[(size_t)(ks * 16 + nt) * 64 + lane] = o;
        } else {
            int gid = (bid - (nkb + 48)) * 256 + tid;
            if (gid < NPOS4) {
                out_tail4[gid] = pos_skip4[gid];
            } else if (gid < NTAIL4) {
                int4 b4 = batch4[gid - NPOS4];
                out_tail4[gid] = make_float4((float)b4.x, (float)b4.y, (float)b4.z, (float)b4.w);
            }
        }
        return;
    }

    // ---- per-block start table (9 binary searches) ----
    if (tid <= NB) {
        int b = tid, lo = 0, hi = Nx;
        while (lo < hi) {
            int mid = (lo + hi) >> 1;
            if (batch[mid] < b) lo = mid + 1; else hi = mid;
        }
        startL[tid] = lo;
    }
    __syncthreads();

    const int i16 = tid >> 4;
    const int i   = bid * 16 + i16;
    const int sub = tid & (GL - 1);

    float py0 = pos_skip[i * 3], py1 = pos_skip[i * 3 + 1], py2 = pos_skip[i * 3 + 2];
    int bb = batch_skip[i];
    int s = startL[bb], e = startL[bb + 1];
    float ysq = py0 * py0 + py1 * py1 + py2 * py2;

    int b_first = batch_skip[bid * 16];
    int b_last  = batch_skip[bid * 16 + 15];
    int s0 = startL[b_first];
    int span = startL[b_last + 1] - s0;
    bool staged = (span <= KCAP);
    if (staged) {
        for (int t = tid; t < span; t += 256) {
            float qx = pos[(s0 + t) * 3], qy = pos[(s0 + t) * 3 + 1], qz = pos[(s0 + t) * 3 + 2];
            seg[t] = make_float4(qx, qy, qz, qx * qx + qy * qy + qz * qz);
        }
        __syncthreads();
    }

    const float FBIG = 3.38e38f;
    float a0 = __int_as_float(0x7f800000), a1 = a0, a2 = a0;
    float b0 = a0, b1v = a0, b2 = a0;
    int   ia0 = 0x7fffffff, ia1 = 0x7fffffff, ia2 = 0x7fffffff;
    int   ib0 = 0x7fffffff, ib1 = 0x7fffffff, ib2 = 0x7fffffff;

    if (staged) {
        for (int jb = s + sub; jb < e; jb += GL * UNR) {
            int j0 = jb, j1 = jb + GL, j2 = jb + 2 * GL, j3 = jb + 3 * GL;
            float4 v0 = seg[j0 - s0];
            float4 v1 = seg[j1 - s0];
            float4 v2 = seg[j2 - s0];
            float4 v3 = seg[j3 - s0];
            float t0 = fmaf(py2, v0.z, fmaf(py1, v0.y, py0 * v0.x));
            float t1 = fmaf(py2, v1.z, fmaf(py1, v1.y, py0 * v1.x));
            float t2 = fmaf(py2, v2.z, fmaf(py1, v2.y, py0 * v2.x));
            float t3 = fmaf(py2, v3.z, fmaf(py1, v3.y, py0 * v3.x));
            float dd0 = fmaf(-2.f, t0, ysq + v0.w);
            float dd1 = fmaf(-2.f, t1, ysq + v1.w);
            float dd2 = fmaf(-2.f, t2, ysq + v2.w);
            float dd3 = fmaf(-2.f, t3, ysq + v3.w);
            dd1 = (j1 < e) ? dd1 : FBIG;
            dd2 = (j2 < e) ? dd2 : FBIG;
            dd3 = (j3 < e) ? dd3 : FBIG;
            ins3f(dd0, j0, a0, ia0, a1, ia1, a2, ia2);
            ins3f(dd1, j1, b0, ib0, b1v, ib1, b2, ib2);
            ins3f(dd2, j2, a0, ia0, a1, ia1, a2, ia2);
            ins3f(dd3, j3, b0, ib0, b1v, ib1, b2, ib2);
        }
    } else {
        for (int jb = s + sub; jb < e; jb += GL * UNR) {
            int j0 = jb;
            int j1 = jb + GL, j2 = jb + 2 * GL, j3 = jb + 3 * GL;
            int c1 = (j1 < e) ? j1 : s;
            int c2 = (j2 < e) ? j2 : s;
            int c3 = (j3 < e) ? j3 : s;
            float qx0 = pos[j0 * 3], qy0 = pos[j0 * 3 + 1], qz0 = pos[j0 * 3 + 2];
            float qx1 = pos[c1 * 3], qy1 = pos[c1 * 3 + 1], qz1 = pos[c1 * 3 + 2];
            float qx2 = pos[c2 * 3], qy2 = pos[c2 * 3 + 1], qz2 = pos[c2 * 3 + 2];
            float qx3 = pos[c3 * 3], qy3 = pos[c3 * 3 + 1], qz3 = pos[c3 * 3 + 2];
            float w0 = qx0 * qx0 + qy0 * qy0 + qz0 * qz0;
            float w1 = qx1 * qx1 + qy1 * qy1 + qz1 * qz1;
            float w2 = qx2 * qx2 + qy2 * qy2 + qz2 * qz2;
            float w3 = qx3 * qx3 + qy3 * qy3 + qz3 * qz3;
            float t0 = fmaf(py2, qz0, fmaf(py1, qy0, py0 * qx0));
            float t1 = fmaf(py2, qz1, fmaf(py1, qy1, py0 * qx1));
            float t2 = fmaf(py2, qz2, fmaf(py1, qy2, py0 * qx2));
            float t3 = fmaf(py2, qz3, fmaf(py1, qy3, py0 * qx3));
            float dd0 = fmaf(-2.f, t0, ysq + w0);
            float dd1 = fmaf(-2.f, t1, ysq + w1);
            float dd2 = fmaf(-2.f, t2, ysq + w2);
            float dd3 = fmaf(-2.f, t3, ysq + w3);
            dd1 = (j1 < e) ? dd1 : FBIG;
            dd2 = (j2 < e) ? dd2 : FBIG;
            dd3 = (j3 < e) ? dd3 : FBIG;
            ins3f(dd0, j0, a0, ia0, a1, ia1, a2, ia2);
            ins3f(dd1, j1, b0, ib0, b1v, ib1, b2, ib2);
            ins3f(dd2, j2, a0, ia0, a1, ia1, a2, ia2);
            ins3f(dd3, j3, b0, ib0, b1v, ib1, b2, ib2);
        }
    }

    ins3t(b0, ib0, a0, ia0, a1, ia1, a2, ia2);
    ins3t(b1v, ib1, a0, ia0, a1, ia1, a2, ia2);
    ins3t(b2, ib2, a0, ia0, a1, ia1, a2, ia2);

    #pragma unroll
    for (int off = 1; off < GL; off <<= 1) {
        float e0 = __shfl_xor(a0, off), e1 = __shfl_xor(a1, off), e2 = __shfl_xor(a2, off);
        int   j0 = __shfl_xor(ia0, off), j1 = __shfl_xor(ia1, off), j2 = __shfl_xor(ia2, off);
        ins3t(e0, j0, a0, ia0, a1, ia1, a2, ia2);
        ins3t(e1, j1, a0, ia0, a1, ia1, a2, ia2);
        ins3t(e2, j2, a0, ia0, a1, ia1, a2, ia2);
    }

    if (sub == 0) {
        int jj0 = (ia0 == 0x7fffffff) ? 0 : ia0;
        int jj1 = (ia1 == 0x7fffffff) ? 0 : ia1;
        int jj2 = (ia2 == 0x7fffffff) ? 0 : ia2;
        idxL[i16][0] = jj0; idxL[i16][1] = jj1; idxL[i16][2] = jj2;
        int jt[3] = { jj0, jj1, jj2 };
        #pragma unroll
        for (int t = 0; t < KNEI; ++t) {
            int j = jt[t];
            float dx = pos[j * 3]     - py0;
            float dy = pos[j * 3 + 1] - py1;
            float dz = pos[j * 3 + 2] - py2;
            float sqd = dx * dx + dy * dy + dz * dz;
            wL[i16][t] = 1.f / fmaxf(sqd, 1e-16f);
        }
    }
    __syncthreads();

    // ---- fused gather + att partial dots (consecutive lanes same row) ----
    const int row16 = tid >> 4, p = tid & 15;
    const int grow = bid * 16 + row16;
    const int g0 = idxL[row16][0];
    const int g1 = idxL[row16][1];
    const int g2 = idxL[row16][2];

    float4 xr0[2][2], xr1[2][2], xr2[2][2];
    float pd0 = 0.f, pd1 = 0.f, pd2 = 0.f;
    #pragma unroll
    for (int u = 0; u < 2; ++u) {
        const int k0 = (p + 16 * u) * 8;
        const float4* q0 = reinterpret_cast<const float4*>(x + (size_t)g0 * CIN + k0);
        const float4* q1 = reinterpret_cast<const float4*>(x + (size_t)g1 * CIN + k0);
        const float4* q2 = reinterpret_cast<const float4*>(x + (size_t)g2 * CIN + k0);
        const float4* wq = reinterpret_cast<const float4*>(w_att + k0);
        #pragma unroll
        for (int h = 0; h < 2; ++h) {
            float4 a = q0[h], b = q1[h], c = q2[h], wv = wq[h];
            xr0[u][h] = a; xr1[u][h] = b; xr2[u][h] = c;
            pd0 += a.x * wv.x + a.y * wv.y + a.z * wv.z + a.w * wv.w;
            pd1 += b.x * wv.x + b.y * wv.y + b.z * wv.z + b.w * wv.w;
            pd2 += c.x * wv.x + c.y * wv.y + c.z * wv.z + c.w * wv.w;
        }
    }
    attP[0][row16][p] = pd0;
    attP[1][row16][p] = pd1;
    attP[2][row16][p] = pd2;
    __syncthreads();

    if (tid < 16) {
        float av0 = 0.f, av1 = 0.f, av2 = 0.f;
        #pragma unroll
        for (int pp = 0; pp < 16; ++pp) {
            av0 += attP[0][tid][pp];
            av1 += attP[1][tid][pp];
            av2 += attP[2][tid][pp];
        }
        float m  = fmaxf(av0, fmaxf(av1, av2));
        float e0s = expf(av0 - m), e1s = expf(av1 - m), e2s = expf(av2 - m);
        float se  = e0s + e1s + e2s;
        float den = wL[tid][0] + wL[tid][1] + wL[tid][2];
        float inv = 1.f / (se * den);
        coefL[tid][0] = wL[tid][0] * e0s * inv;
        coefL[tid][1] = wL[tid][1] * e1s * inv;
        coefL[tid][2] = wL[tid][2] * e2s * inv;
    }
    __syncthreads();

    // ---- combine from registers -> bf16 A-fragments -> Abuf ----
    {
        const float c0 = coefL[row16][0];
        const float c1 = coefL[row16][1];
        const float c2 = coefL[row16][2];
        #pragma unroll
        for (int u = 0; u < 3; ++u) {
            const int cidx = p + 16 * u;        // 0..47
            float v[8];
            if (u < 2) {
                #pragma unroll
                for (int h = 0; h < 2; ++h) {
                    float4 a = xr0[u][h], b = xr1[u][h], c = xr2[u][h];
                    v[h * 4 + 0] = c0 * a.x + c1 * b.x + c2 * c.x;
                    v[h * 4 + 1] = c0 * a.y + c1 * b.y + c2 * c.y;
                    v[h * 4 + 2] = c0 * a.z + c1 * b.z + c2 * c.z;
                    v[h * 4 + 3] = c0 * a.w + c1 * b.w + c2 * c.w;
                }
            } else {
                const float4* ps = reinterpret_cast<const float4*>(
                    x_skip + (size_t)grow * CSK + (cidx * 8 - CIN));
                #pragma unroll
                for (int h = 0; h < 2; ++h) {
                    float4 a = ps[h];
                    v[h * 4 + 0] = a.x; v[h * 4 + 1] = a.y;
                    v[h * 4 + 2] = a.z; v[h * 4 + 3] = a.w;
                }
            }
            ushort uu[8];
            #pragma unroll
            for (int j = 0; j < 8; ++j) uu[j] = f2bf(v[j]);
            uint4 o;
            o.x = (unsigned)uu[0] | ((unsigned)uu[1] << 16);
            o.y = (unsigned)uu[2] | ((unsigned)uu[3] << 16);
            o.z = (unsigned)uu[4] | ((unsigned)uu[5] << 16);
            o.w = (unsigned)uu[6] | ((unsigned)uu[7] << 16);
            const int ks = cidx >> 2, kg = cidx & 3;
            Abuf[((size_t)bid * NKS + ks) * 64 + row16 + 16 * kg] = o;
        }
    }
}

// K2: MFMA GEMM, B-half staged in LDS once; A prefetched to registers.
// h stored BF16 (stats from f32 accumulators before rounding).
__global__ __launch_bounds__(512) void k_gemm(
    const uint4* __restrict__ Abuf, const uint4* __restrict__ Bbuf,
    const float* __restrict__ b1, ushort* __restrict__ hb16,
    float* __restrict__ psum, float* __restrict__ psq) {
    __shared__ uint4 Bls[NKS * 8 * 64];   // 96 KB
    __shared__ float SS[8][128], QQ[8][128];
    const int tid = threadIdx.x;
    const int w = tid >> 6, lane = tid & 63;
    const int half = blockIdx.x & 1;
    const int strip = (blockIdx.x >> 1) * 8 + w;

    bf16x8 afr[NKS];
    #pragma unroll
    for (int ks = 0; ks < NKS; ++ks)
        afr[ks] = *reinterpret_cast<const bf16x8*>(
            Abuf + ((size_t)strip * NKS + ks) * 64 + lane);

    #pragma unroll
    for (int ks = 0; ks < NKS; ++ks)
        Bls[ks * 512 + tid] = Bbuf[(size_t)(ks * 16 + half * 8) * 64 + tid];
    __syncthreads();

    f32x4 acc[8];
    #pragma unroll
    for (int nt = 0; nt < 8; ++nt) acc[nt] = (f32x4)(0.f);

    #pragma unroll
    for (int ks = 0; ks < NKS; ++ks) {
        #pragma unroll
        for (int nt = 0; nt < 8; ++nt) {
            bf16x8 bfr = *reinterpret_cast<const bf16x8*>(
                &Bls[ks * 512 + nt * 64 + lane]);
            acc[nt] = __builtin_amdgcn_mfma_f32_16x16x32_bf16(afr[ks], bfr, acc[nt], 0, 0, 0);
        }
    }

    // epilogue: +bias, store h (bf16), per-wave column stats from f32 accs
    const int col16 = lane & 15, rg = lane >> 4;
    const int rowb = strip * 16 + rg * 4;
    float s_[8], q_[8];
    #pragma unroll
    for (int nt = 0; nt < 8; ++nt) {
        const int chg = half * 128 + nt * 16 + col16;
        float bn = b1[chg];
        float s = 0.f, q = 0.f;
        #pragma unroll
        for (int r = 0; r < 4; ++r) {
            float v = acc[nt][r] + bn;
            hb16[(size_t)(rowb + r) * CO + chg] = f2bf(v);
            s += v; q += v * v;
        }
        s += __shfl_xor(s, 16); s += __shfl_xor(s, 32);
        q += __shfl_xor(q, 16); q += __shfl_xor(q, 32);
        s_[nt] = s; q_[nt] = q;
    }
    if (lane < 16) {
        #pragma unroll
        for (int nt = 0; nt < 8; ++nt) {
            SS[w][nt * 16 + lane] = s_[nt];
            QQ[w][nt * 16 + lane] = q_[nt];
        }
    }
    __syncthreads();
    if (tid < 128) {
        float s = ((SS[0][tid] + SS[1][tid]) + (SS[2][tid] + SS[3][tid]))
                + ((SS[4][tid] + SS[5][tid]) + (SS[6][tid] + SS[7][tid]));
        float q = ((QQ[0][tid] + QQ[1][tid]) + (QQ[2][tid] + QQ[3][tid]))
                + ((QQ[4][tid] + QQ[5][tid]) + (QQ[6][tid] + QQ[7][tid]));
        psum[(size_t)blockIdx.x * 128 + tid] = s;   // [block][local-channel]
        psq [(size_t)blockIdx.x * 128 + tid] = q;
    }
}

// K3: reduce partials -> mean/var -> scale/shift per channel (1 block, 1024 thr)
__global__ void k_stats(const float* __restrict__ psum, const float* __restrict__ psq,
                        const float* __restrict__ gamma, const float* __restrict__ beta,
                        float* __restrict__ sscale, int Ny) {
    __shared__ float sred[4][256], qred[4][256];
    int c  = threadIdx.x & 255;
    int ch = threadIdx.x >> 8;       // chunk 0..3 over g
    int half = c >> 7, local = c & 127;
    float s = 0.f, q = 0.f;
    for (int g = ch * 32; g < ch * 32 + 32; ++g) {
        size_t idx = (size_t)(2 * g + half) * 128 + local;
        s += psum[idx];
        q += psq [idx];
    }
    sred[ch][c] = s; qred[ch][c] = q;
    __syncthreads();
    if (ch == 0) {
        float S = ((sred[0][c] + sred[1][c]) + (sred[2][c] + sred[3][c]));
        float Q = ((qred[0][c] + qred[1][c]) + (qred[2][c] + qred[3][c]));
        float mean = S / (float)Ny;
        float var  = Q / (float)Ny - mean * mean;
        float rstd = rsqrtf(var + 1e-6f);
        float sc = gamma[c] * rstd;
        sscale[c]       = sc;
        sscale[256 + c] = beta[c] - mean * sc;
    }
}

// K4: read bf16 h (8 elems/thread), BN apply + LeakyReLU, write f32 out.
__global__ void k_final(const ushort* __restrict__ hb16,
                        const float* __restrict__ sscale,
                        float* __restrict__ outp, int total8) {
    for (int t = blockIdx.x * blockDim.x + threadIdx.x; t < total8;
         t += gridDim.x * blockDim.x) {
        int c8 = (t & (CO / 8 - 1)) * 8;
        uint4 hv = *reinterpret_cast<const uint4*>(hb16 + (size_t)t * 8);
        const float4* scp = reinterpret_cast<const float4*>(sscale + c8);
        const float4* shp = reinterpret_cast<const float4*>(sscale + 256 + c8);
        float4 sc0 = scp[0], sc1 = scp[1];
        float4 sh0 = shp[0], sh1 = shp[1];
        float h0 = bf2f((ushort)(hv.x & 0xffff));
        float h1 = bf2f((ushort)(hv.x >> 16));
        float h2 = bf2f((ushort)(hv.y & 0xffff));
        float h3 = bf2f((ushort)(hv.y >> 16));
        float h4 = bf2f((ushort)(hv.z & 0xffff));
        float h5 = bf2f((ushort)(hv.z >> 16));
        float h6 = bf2f((ushort)(hv.w & 0xffff));
        float h7 = bf2f((ushort)(hv.w >> 16));
        float4 o0, o1;
        o0.x = h0 * sc0.x + sh0.x; o0.x = o0.x > 0.f ? o0.x : 0.2f * o0.x;
        o0.y = h1 * sc0.y + sh0.y; o0.y = o0.y > 0.f ? o0.y : 0.2f * o0.y;
        o0.z = h2 * sc0.z + sh0.z; o0.z = o0.z > 0.f ? o0.z : 0.2f * o0.z;
        o0.w = h3 * sc0.w + sh0.w; o0.w = o0.w > 0.f ? o0.w : 0.2f * o0.w;
        o1.x = h4 * sc1.x + sh1.x; o1.x = o1.x > 0.f ? o1.x : 0.2f * o1.x;
        o1.y = h5 * sc1.y + sh1.y; o1.y = o1.y > 0.f ? o1.y : 0.2f * o1.y;
        o1.z = h6 * sc1.z + sh1.z; o1.z = o1.z > 0.f ? o1.z : 0.2f * o1.z;
        o1.w = h7 * sc1.w + sh1.w; o1.w = o1.w > 0.f ? o1.w : 0.2f * o1.w;
        float4* op = reinterpret_cast<float4*>(outp + (size_t)t * 8);
        op[0] = o0;
        op[1] = o1;
    }
}

extern "C" void kernel_launch(void* const* d_in, const int* in_sizes, int n_in,
                              void* d_out, int out_size, void* d_ws, size_t ws_size,
                              hipStream_t stream) {
    const float* x         = (const float*)d_in[0];
    const float* pos       = (const float*)d_in[1];
    const int*   batch     = (const int*)d_in[2];
    const float* x_skip    = (const float*)d_in[3];
    const float* pos_skip  = (const float*)d_in[4];
    const int*   batch_skip= (const int*)d_in[5];
    const float* w_att     = (const float*)d_in[6];
    const float* W1        = (const float*)d_in[7];
    const float* b1        = (const float*)d_in[8];
    const float* gamma     = (const float*)d_in[9];
    const float* beta      = (const float*)d_in[10];

    const int Nx = in_sizes[2];      // 4096
    const int Ny = in_sizes[5];      // 16384
    const int NB = 8;
    const int strips  = Ny / 16;     // 1024
    const int gblocks = strips / 8 * 2;   // 256 gemm blocks (8 strips x 2 halves)

    char* w = (char*)d_ws;
    uint4*  Abuf     = (uint4*)w;  w += (size_t)strips * NKS * 64 * 16;   // 12.6 MB
    uint4*  Bbuf     = (uint4*)w;  w += (size_t)NKS * NNT * 64 * 16;      // 196 KB
    ushort* hb16     = (ushort*)w; w += (size_t)Ny * CO * 2;              // 8.4 MB
    float*  psum     = (float*)w;  w += (size_t)gblocks * 128 * 4;
    float*  psq      = (float*)w;  w += (size_t)gblocks * 128 * 4;
    float*  sscale   = (float*)w;  w += (size_t)512 * 4;

    float* outp = (float*)d_out;                          // [Ny][Co] f32 out
    float4* out_tail4 = (float4*)(outp + (size_t)Ny * CO);
    const float4* pos_skip4 = (const float4*)pos_skip;
    const int4*   batch4    = (const int4*)batch_skip;

    const int total8 = Ny * CO / 8;

    k_main<<<dim3(strips + 48 + 64), dim3(256), 0, stream>>>(
        pos, batch, pos_skip, batch_skip, x, x_skip, w_att, W1,
        Abuf, Bbuf, pos_skip4, batch4, out_tail4, Nx, Ny, NB);
    k_gemm<<<dim3(gblocks), dim3(512), 0, stream>>>(
        Abuf, Bbuf, b1, hb16, psum, psq);
    k_stats<<<dim3(1), dim3(1024), 0, stream>>>(
        psum, psq, gamma, beta, sscale, Ny);
    k_final<<<dim3(2048), dim3(256), 0, stream>>>(hb16, sscale, outp, total8);
}

// Round 19
// 52.041 us; speedup vs baseline: 1.0049x; 1.0049x over previous
//
#include <hip/hip_runtime.h>
#include <math.h>

// ---------------------------------------------------------------------------
// AttentiveFPModule: knn(K=3) attentive interpolate + concat + Linear + BN + LeakyReLU
// Sizes: Nx=4096, Ny=16384, C=256, Cs=128, Co=256, B=4, Kin=384
// 4 launches:
//   k_main : [0,1024) knn scan + fused attv+gather -> Abuf A-fragments
//            [1024,1072) W1 -> Bbuf fragments; [1072,1136) tail outputs
//   k_gemm : MFMA; B-QUARTER (48KB) staged in LDS -> 2-3 blocks/CU
//            (4-6 waves/SIMD); B L2 traffic unchanged vs R16 (24.6MB).
//   k_stats: reduce per-block partials -> BN scale/shift (1 block)
//   k_final: read bf16 h -> BN apply + LeakyReLU -> f32 out
// Lessons: R16 B-LDS -21us (B-L2-bound). R10 fence +29us. R11/R15 occupancy
//   raises with B-in-L2 regressed. R18 bf16-h neutral (h is L2-resident).
//   R19: occupancy raise WITH B-in-LDS (the untested combination).
// ---------------------------------------------------------------------------

#define KNEI 3
#define GL 16           // lanes per y-point in k_main knn
#define UNR 4           // scan unroll
#define KCAP 1280       // staged segment capacity (float4s)
#define CIN 256         // C
#define CSK 128         // Cs
#define CO  256         // Co
#define NKS 12          // Kin / 32
#define NNT 16          // Co / 16
#define NYF 16384.0f
#define NPOS4 12288     // Ny*3/4
#define NTAIL4 16384    // NPOS4 + Ny/4

typedef __attribute__((ext_vector_type(8))) short bf16x8;
typedef __attribute__((ext_vector_type(4))) float f32x4;

__device__ __forceinline__ ushort f2bf(float f) {
    unsigned u = __float_as_uint(f);
    u += 0x7fffu + ((u >> 16) & 1u);
    return (ushort)(u >> 16);
}

__device__ __forceinline__ float bf2f(ushort u) {
    return __uint_as_float(((unsigned)u) << 16);
}

__device__ __forceinline__ bool nless(float da, int ia, float db, int ib) {
    return (da < db) || (da == db && ia < ib);
}

__device__ __forceinline__ void ins3f(float dd, int j,
                                      float& d0, int& i0,
                                      float& d1, int& i1,
                                      float& d2, int& i2) {
    bool l0 = dd < d0;
    bool l1 = dd < d1;
    bool l2 = dd < d2;
    float n2 = l1 ? d1 : (l2 ? dd : d2); int m2 = l1 ? i1 : (l2 ? j : i2);
    float n1 = l0 ? d0 : (l1 ? dd : d1); int m1 = l0 ? i0 : (l1 ? j : i1);
    float n0 = l0 ? dd : d0;             int m0 = l0 ? j  : i0;
    d0 = n0; i0 = m0; d1 = n1; i1 = m1; d2 = n2; i2 = m2;
}

__device__ __forceinline__ void ins3t(float dd, int j,
                                      float& d0, int& i0,
                                      float& d1, int& i1,
                                      float& d2, int& i2) {
    bool l0 = nless(dd, j, d0, i0);
    bool l1 = nless(dd, j, d1, i1);
    bool l2 = nless(dd, j, d2, i2);
    float n2 = l1 ? d1 : (l2 ? dd : d2); int m2 = l1 ? i1 : (l2 ? j : i2);
    float n1 = l0 ? d0 : (l1 ? dd : d1); int m1 = l0 ? i0 : (l1 ? j : i1);
    float n0 = l0 ? dd : d0;             int m0 = l0 ? j  : i0;
    d0 = n0; i0 = m0; d1 = n1; i1 = m1; d2 = n2; i2 = m2;
}

// K1 (multi-role by block range):
//   [0, Ny/16)              : knn + fused attv/gather -> Abuf
//   [Ny/16, Ny/16+48)       : W1 -> Bbuf MFMA B-fragments (bf16)
//   [Ny/16+48, Ny/16+48+64) : tail outputs
__global__ __launch_bounds__(256) void k_main(
                      const float* __restrict__ pos,
                      const int* __restrict__ batch,
                      const float* __restrict__ pos_skip,
                      const int* __restrict__ batch_skip,
                      const float* __restrict__ x,
                      const float* __restrict__ x_skip,
                      const float* __restrict__ w_att,
                      const float* __restrict__ W1,
                      uint4* __restrict__ Abuf, uint4* __restrict__ Bbuf,
                      const float4* __restrict__ pos_skip4,
                      const int4* __restrict__ batch4,
                      float4* __restrict__ out_tail4,
                      int Nx, int Ny, int NB) {
    __shared__ float4 seg[KCAP + 48];
    __shared__ int   startL[12];
    __shared__ int   idxL[16][3];
    __shared__ float wL[16][3];
    __shared__ float coefL[16][3];
    __shared__ float attP[3][16][16];
    const int bid = blockIdx.x;
    const int nkb = Ny >> 4;             // 1024
    const int tid = threadIdx.x;

    if (bid >= nkb) {
        if (bid < nkb + 48) {
            int wave = tid >> 6, lane = tid & 63;
            int p  = (bid - nkb) * 4 + wave;   // 0..191
            int ks = p >> 4, nt = p & 15;
            int kb = ks * 32 + (lane >> 4) * 8;
            int n  = nt * 16 + (lane & 15);
            ushort u[8];
            #pragma unroll
            for (int j = 0; j < 8; ++j)
                u[j] = f2bf(W1[(size_t)(kb + j) * CO + n]);
            uint4 o;
            o.x = (unsigned)u[0] | ((unsigned)u[1] << 16);
            o.y = (unsigned)u[2] | ((unsigned)u[3] << 16);
            o.z = (unsigned)u[4] | ((unsigned)u[5] << 16);
            o.w = (unsigned)u[6] | ((unsigned)u[7] << 16);
            Bbuf[(size_t)(ks * 16 + nt) * 64 + lane] = o;
        } else {
            int gid = (bid - (nkb + 48)) * 256 + tid;
            if (gid < NPOS4) {
                out_tail4[gid] = pos_skip4[gid];
            } else if (gid < NTAIL4) {
                int4 b4 = batch4[gid - NPOS4];
                out_tail4[gid] = make_float4((float)b4.x, (float)b4.y, (float)b4.z, (float)b4.w);
            }
        }
        return;
    }

    // ---- per-block start table (9 binary searches) ----
    if (tid <= NB) {
        int b = tid, lo = 0, hi = Nx;
        while (lo < hi) {
            int mid = (lo + hi) >> 1;
            if (batch[mid] < b) lo = mid + 1; else hi = mid;
        }
        startL[tid] = lo;
    }
    __syncthreads();

    const int i16 = tid >> 4;
    const int i   = bid * 16 + i16;
    const int sub = tid & (GL - 1);

    float py0 = pos_skip[i * 3], py1 = pos_skip[i * 3 + 1], py2 = pos_skip[i * 3 + 2];
    int bb = batch_skip[i];
    int s = startL[bb], e = startL[bb + 1];
    float ysq = py0 * py0 + py1 * py1 + py2 * py2;

    int b_first = batch_skip[bid * 16];
    int b_last  = batch_skip[bid * 16 + 15];
    int s0 = startL[b_first];
    int span = startL[b_last + 1] - s0;
    bool staged = (span <= KCAP);
    if (staged) {
        for (int t = tid; t < span; t += 256) {
            float qx = pos[(s0 + t) * 3], qy = pos[(s0 + t) * 3 + 1], qz = pos[(s0 + t) * 3 + 2];
            seg[t] = make_float4(qx, qy, qz, qx * qx + qy * qy + qz * qz);
        }
        __syncthreads();
    }

    const float FBIG = 3.38e38f;
    float a0 = __int_as_float(0x7f800000), a1 = a0, a2 = a0;
    float b0 = a0, b1v = a0, b2 = a0;
    int   ia0 = 0x7fffffff, ia1 = 0x7fffffff, ia2 = 0x7fffffff;
    int   ib0 = 0x7fffffff, ib1 = 0x7fffffff, ib2 = 0x7fffffff;

    if (staged) {
        for (int jb = s + sub; jb < e; jb += GL * UNR) {
            int j0 = jb, j1 = jb + GL, j2 = jb + 2 * GL, j3 = jb + 3 * GL;
            float4 v0 = seg[j0 - s0];
            float4 v1 = seg[j1 - s0];
            float4 v2 = seg[j2 - s0];
            float4 v3 = seg[j3 - s0];
            float t0 = fmaf(py2, v0.z, fmaf(py1, v0.y, py0 * v0.x));
            float t1 = fmaf(py2, v1.z, fmaf(py1, v1.y, py0 * v1.x));
            float t2 = fmaf(py2, v2.z, fmaf(py1, v2.y, py0 * v2.x));
            float t3 = fmaf(py2, v3.z, fmaf(py1, v3.y, py0 * v3.x));
            float dd0 = fmaf(-2.f, t0, ysq + v0.w);
            float dd1 = fmaf(-2.f, t1, ysq + v1.w);
            float dd2 = fmaf(-2.f, t2, ysq + v2.w);
            float dd3 = fmaf(-2.f, t3, ysq + v3.w);
            dd1 = (j1 < e) ? dd1 : FBIG;
            dd2 = (j2 < e) ? dd2 : FBIG;
            dd3 = (j3 < e) ? dd3 : FBIG;
            ins3f(dd0, j0, a0, ia0, a1, ia1, a2, ia2);
            ins3f(dd1, j1, b0, ib0, b1v, ib1, b2, ib2);
            ins3f(dd2, j2, a0, ia0, a1, ia1, a2, ia2);
            ins3f(dd3, j3, b0, ib0, b1v, ib1, b2, ib2);
        }
    } else {
        for (int jb = s + sub; jb < e; jb += GL * UNR) {
            int j0 = jb;
            int j1 = jb + GL, j2 = jb + 2 * GL, j3 = jb + 3 * GL;
            int c1 = (j1 < e) ? j1 : s;
            int c2 = (j2 < e) ? j2 : s;
            int c3 = (j3 < e) ? j3 : s;
            float qx0 = pos[j0 * 3], qy0 = pos[j0 * 3 + 1], qz0 = pos[j0 * 3 + 2];
            float qx1 = pos[c1 * 3], qy1 = pos[c1 * 3 + 1], qz1 = pos[c1 * 3 + 2];
            float qx2 = pos[c2 * 3], qy2 = pos[c2 * 3 + 1], qz2 = pos[c2 * 3 + 2];
            float qx3 = pos[c3 * 3], qy3 = pos[c3 * 3 + 1], qz3 = pos[c3 * 3 + 2];
            float w0 = qx0 * qx0 + qy0 * qy0 + qz0 * qz0;
            float w1 = qx1 * qx1 + qy1 * qy1 + qz1 * qz1;
            float w2 = qx2 * qx2 + qy2 * qy2 + qz2 * qz2;
            float w3 = qx3 * qx3 + qy3 * qy3 + qz3 * qz3;
            float t0 = fmaf(py2, qz0, fmaf(py1, qy0, py0 * qx0));
            float t1 = fmaf(py2, qz1, fmaf(py1, qy1, py0 * qx1));
            float t2 = fmaf(py2, qz2, fmaf(py1, qy2, py0 * qx2));
            float t3 = fmaf(py2, qz3, fmaf(py1, qy3, py0 * qx3));
            float dd0 = fmaf(-2.f, t0, ysq + w0);
            float dd1 = fmaf(-2.f, t1, ysq + w1);
            float dd2 = fmaf(-2.f, t2, ysq + w2);
            float dd3 = fmaf(-2.f, t3, ysq + w3);
            dd1 = (j1 < e) ? dd1 : FBIG;
            dd2 = (j2 < e) ? dd2 : FBIG;
            dd3 = (j3 < e) ? dd3 : FBIG;
            ins3f(dd0, j0, a0, ia0, a1, ia1, a2, ia2);
            ins3f(dd1, j1, b0, ib0, b1v, ib1, b2, ib2);
            ins3f(dd2, j2, a0, ia0, a1, ia1, a2, ia2);
            ins3f(dd3, j3, b0, ib0, b1v, ib1, b2, ib2);
        }
    }

    ins3t(b0, ib0, a0, ia0, a1, ia1, a2, ia2);
    ins3t(b1v, ib1, a0, ia0, a1, ia1, a2, ia2);
    ins3t(b2, ib2, a0, ia0, a1, ia1, a2, ia2);

    #pragma unroll
    for (int off = 1; off < GL; off <<= 1) {
        float e0 = __shfl_xor(a0, off), e1 = __shfl_xor(a1, off), e2 = __shfl_xor(a2, off);
        int   j0 = __shfl_xor(ia0, off), j1 = __shfl_xor(ia1, off), j2 = __shfl_xor(ia2, off);
        ins3t(e0, j0, a0, ia0, a1, ia1, a2, ia2);
        ins3t(e1, j1, a0, ia0, a1, ia1, a2, ia2);
        ins3t(e2, j2, a0, ia0, a1, ia1, a2, ia2);
    }

    if (sub == 0) {
        int jj0 = (ia0 == 0x7fffffff) ? 0 : ia0;
        int jj1 = (ia1 == 0x7fffffff) ? 0 : ia1;
        int jj2 = (ia2 == 0x7fffffff) ? 0 : ia2;
        idxL[i16][0] = jj0; idxL[i16][1] = jj1; idxL[i16][2] = jj2;
        int jt[3] = { jj0, jj1, jj2 };
        #pragma unroll
        for (int t = 0; t < KNEI; ++t) {
            int j = jt[t];
            float dx = pos[j * 3]     - py0;
            float dy = pos[j * 3 + 1] - py1;
            float dz = pos[j * 3 + 2] - py2;
            float sqd = dx * dx + dy * dy + dz * dz;
            wL[i16][t] = 1.f / fmaxf(sqd, 1e-16f);
        }
    }
    __syncthreads();

    // ---- fused gather + att partial dots (consecutive lanes same row) ----
    const int row16 = tid >> 4, p = tid & 15;
    const int grow = bid * 16 + row16;
    const int g0 = idxL[row16][0];
    const int g1 = idxL[row16][1];
    const int g2 = idxL[row16][2];

    float4 xr0[2][2], xr1[2][2], xr2[2][2];
    float pd0 = 0.f, pd1 = 0.f, pd2 = 0.f;
    #pragma unroll
    for (int u = 0; u < 2; ++u) {
        const int k0 = (p + 16 * u) * 8;
        const float4* q0 = reinterpret_cast<const float4*>(x + (size_t)g0 * CIN + k0);
        const float4* q1 = reinterpret_cast<const float4*>(x + (size_t)g1 * CIN + k0);
        const float4* q2 = reinterpret_cast<const float4*>(x + (size_t)g2 * CIN + k0);
        const float4* wq = reinterpret_cast<const float4*>(w_att + k0);
        #pragma unroll
        for (int h = 0; h < 2; ++h) {
            float4 a = q0[h], b = q1[h], c = q2[h], wv = wq[h];
            xr0[u][h] = a; xr1[u][h] = b; xr2[u][h] = c;
            pd0 += a.x * wv.x + a.y * wv.y + a.z * wv.z + a.w * wv.w;
            pd1 += b.x * wv.x + b.y * wv.y + b.z * wv.z + b.w * wv.w;
            pd2 += c.x * wv.x + c.y * wv.y + c.z * wv.z + c.w * wv.w;
        }
    }
    attP[0][row16][p] = pd0;
    attP[1][row16][p] = pd1;
    attP[2][row16][p] = pd2;
    __syncthreads();

    if (tid < 16) {
        float av0 = 0.f, av1 = 0.f, av2 = 0.f;
        #pragma unroll
        for (int pp = 0; pp < 16; ++pp) {
            av0 += attP[0][tid][pp];
            av1 += attP[1][tid][pp];
            av2 += attP[2][tid][pp];
        }
        float m  = fmaxf(av0, fmaxf(av1, av2));
        float e0s = expf(av0 - m), e1s = expf(av1 - m), e2s = expf(av2 - m);
        float se  = e0s + e1s + e2s;
        float den = wL[tid][0] + wL[tid][1] + wL[tid][2];
        float inv = 1.f / (se * den);
        coefL[tid][0] = wL[tid][0] * e0s * inv;
        coefL[tid][1] = wL[tid][1] * e1s * inv;
        coefL[tid][2] = wL[tid][2] * e2s * inv;
    }
    __syncthreads();

    // ---- combine from registers -> bf16 A-fragments -> Abuf ----
    {
        const float c0 = coefL[row16][0];
        const float c1 = coefL[row16][1];
        const float c2 = coefL[row16][2];
        #pragma unroll
        for (int u = 0; u < 3; ++u) {
            const int cidx = p + 16 * u;        // 0..47
            float v[8];
            if (u < 2) {
                #pragma unroll
                for (int h = 0; h < 2; ++h) {
                    float4 a = xr0[u][h], b = xr1[u][h], c = xr2[u][h];
                    v[h * 4 + 0] = c0 * a.x + c1 * b.x + c2 * c.x;
                    v[h * 4 + 1] = c0 * a.y + c1 * b.y + c2 * c.y;
                    v[h * 4 + 2] = c0 * a.z + c1 * b.z + c2 * c.z;
                    v[h * 4 + 3] = c0 * a.w + c1 * b.w + c2 * c.w;
                }
            } else {
                const float4* ps = reinterpret_cast<const float4*>(
                    x_skip + (size_t)grow * CSK + (cidx * 8 - CIN));
                #pragma unroll
                for (int h = 0; h < 2; ++h) {
                    float4 a = ps[h];
                    v[h * 4 + 0] = a.x; v[h * 4 + 1] = a.y;
                    v[h * 4 + 2] = a.z; v[h * 4 + 3] = a.w;
                }
            }
            ushort uu[8];
            #pragma unroll
            for (int j = 0; j < 8; ++j) uu[j] = f2bf(v[j]);
            uint4 o;
            o.x = (unsigned)uu[0] | ((unsigned)uu[1] << 16);
            o.y = (unsigned)uu[2] | ((unsigned)uu[3] << 16);
            o.z = (unsigned)uu[4] | ((unsigned)uu[5] << 16);
            o.w = (unsigned)uu[6] | ((unsigned)uu[7] << 16);
            const int ks = cidx >> 2, kg = cidx & 3;
            Abuf[((size_t)bid * NKS + ks) * 64 + row16 + 16 * kg] = o;
        }
    }
}

// K2: MFMA GEMM, B-QUARTER (48KB) staged in LDS -> 2-3 blocks/CU.
// 512 blocks x 8 waves; block b: quarter q = b&3 (64 cols), strips
// (b>>2)*8 + w. B L2 traffic unchanged (512 x 48KB = 24.6MB); A read 4x
// (50MB L2, cheap). A prefetched to registers; h stored bf16.
__global__ __launch_bounds__(512, 4) void k_gemm(
    const uint4* __restrict__ Abuf, const uint4* __restrict__ Bbuf,
    const float* __restrict__ b1, ushort* __restrict__ hb16,
    float* __restrict__ psum, float* __restrict__ psq) {
    __shared__ uint4 Bls[NKS * 4 * 64];   // 48 KB
    __shared__ float SS[8][64], QQ[8][64];
    const int tid = threadIdx.x;
    const int w = tid >> 6, lane = tid & 63;
    const int q = blockIdx.x & 3;
    const int strip = (blockIdx.x >> 2) * 8 + w;

    // prefetch all 12 A-fragments
    bf16x8 afr[NKS];
    #pragma unroll
    for (int ks = 0; ks < NKS; ++ks)
        afr[ks] = *reinterpret_cast<const bf16x8*>(
            Abuf + ((size_t)strip * NKS + ks) * 64 + lane);

    // stage this quarter's B fragments: Bls[ks*256 + rem] = Bbuf[ks*1024 + q*256 + rem]
    #pragma unroll
    for (int it = 0; it < 6; ++it) {
        int idx = it * 512 + tid;
        int ks = idx >> 8, rem = idx & 255;
        Bls[idx] = Bbuf[(size_t)ks * 1024 + q * 256 + rem];
    }
    __syncthreads();

    f32x4 acc[4];
    #pragma unroll
    for (int nt = 0; nt < 4; ++nt) acc[nt] = (f32x4)(0.f);

    #pragma unroll
    for (int ks = 0; ks < NKS; ++ks) {
        #pragma unroll
        for (int nt = 0; nt < 4; ++nt) {
            bf16x8 bfr = *reinterpret_cast<const bf16x8*>(
                &Bls[ks * 256 + nt * 64 + lane]);
            acc[nt] = __builtin_amdgcn_mfma_f32_16x16x32_bf16(afr[ks], bfr, acc[nt], 0, 0, 0);
        }
    }

    // epilogue: +bias, store h (bf16), per-wave column stats from f32 accs
    const int col16 = lane & 15, rg = lane >> 4;
    const int rowb = strip * 16 + rg * 4;
    float s_[4], q_[4];
    #pragma unroll
    for (int nt = 0; nt < 4; ++nt) {
        const int chg = q * 64 + nt * 16 + col16;
        float bn = b1[chg];
        float s = 0.f, qq = 0.f;
        #pragma unroll
        for (int r = 0; r < 4; ++r) {
            float v = acc[nt][r] + bn;
            hb16[(size_t)(rowb + r) * CO + chg] = f2bf(v);
            s += v; qq += v * v;
        }
        s += __shfl_xor(s, 16); s += __shfl_xor(s, 32);
        qq += __shfl_xor(qq, 16); qq += __shfl_xor(qq, 32);
        s_[nt] = s; q_[nt] = qq;
    }
    if (lane < 16) {
        #pragma unroll
        for (int nt = 0; nt < 4; ++nt) {
            SS[w][nt * 16 + lane] = s_[nt];
            QQ[w][nt * 16 + lane] = q_[nt];
        }
    }
    __syncthreads();
    if (tid < 64) {
        float s = ((SS[0][tid] + SS[1][tid]) + (SS[2][tid] + SS[3][tid]))
                + ((SS[4][tid] + SS[5][tid]) + (SS[6][tid] + SS[7][tid]));
        float qq = ((QQ[0][tid] + QQ[1][tid]) + (QQ[2][tid] + QQ[3][tid]))
                 + ((QQ[4][tid] + QQ[5][tid]) + (QQ[6][tid] + QQ[7][tid]));
        psum[(size_t)blockIdx.x * 64 + tid] = s;   // [block][local-channel]
        psq [(size_t)blockIdx.x * 64 + tid] = qq;
    }
}

// K3: reduce partials -> mean/var -> scale/shift per channel (1 block, 1024 thr)
// psum layout: [512 blocks][64 local]; block b covers quarter b&3.
// channel c: quarter = c>>6, local = c&63; blocks 4g+quarter, g=0..127.
__global__ void k_stats(const float* __restrict__ psum, const float* __restrict__ psq,
                        const float* __restrict__ gamma, const float* __restrict__ beta,
                        float* __restrict__ sscale, int Ny) {
    __shared__ float sred[4][256], qred[4][256];
    int c  = threadIdx.x & 255;
    int ch = threadIdx.x >> 8;       // chunk 0..3 over g
    int quarter = c >> 6, local = c & 63;
    float s = 0.f, q = 0.f;
    for (int g = ch * 32; g < ch * 32 + 32; ++g) {
        size_t idx = (size_t)(4 * g + quarter) * 64 + local;
        s += psum[idx];
        q += psq [idx];
    }
    sred[ch][c] = s; qred[ch][c] = q;
    __syncthreads();
    if (ch == 0) {
        float S = ((sred[0][c] + sred[1][c]) + (sred[2][c] + sred[3][c]));
        float Q = ((qred[0][c] + qred[1][c]) + (qred[2][c] + qred[3][c]));
        float mean = S / (float)Ny;
        float var  = Q / (float)Ny - mean * mean;
        float rstd = rsqrtf(var + 1e-6f);
        float sc = gamma[c] * rstd;
        sscale[c]       = sc;
        sscale[256 + c] = beta[c] - mean * sc;
    }
}

// K4: read bf16 h (8 elems/thread), BN apply + LeakyReLU, write f32 out.
__global__ void k_final(const ushort* __restrict__ hb16,
                        const float* __restrict__ sscale,
                        float* __restrict__ outp, int total8) {
    for (int t = blockIdx.x * blockDim.x + threadIdx.x; t < total8;
         t += gridDim.x * blockDim.x) {
        int c8 = (t & (CO / 8 - 1)) * 8;
        uint4 hv = *reinterpret_cast<const uint4*>(hb16 + (size_t)t * 8);
        const float4* scp = reinterpret_cast<const float4*>(sscale + c8);
        const float4* shp = reinterpret_cast<const float4*>(sscale + 256 + c8);
        float4 sc0 = scp[0], sc1 = scp[1];
        float4 sh0 = shp[0], sh1 = shp[1];
        float h0 = bf2f((ushort)(hv.x & 0xffff));
        float h1 = bf2f((ushort)(hv.x >> 16));
        float h2 = bf2f((ushort)(hv.y & 0xffff));
        float h3 = bf2f((ushort)(hv.y >> 16));
        float h4 = bf2f((ushort)(hv.z & 0xffff));
        float h5 = bf2f((ushort)(hv.z >> 16));
        float h6 = bf2f((ushort)(hv.w & 0xffff));
        float h7 = bf2f((ushort)(hv.w >> 16));
        float4 o0, o1;
        o0.x = h0 * sc0.x + sh0.x; o0.x = o0.x > 0.f ? o0.x : 0.2f * o0.x;
        o0.y = h1 * sc0.y + sh0.y; o0.y = o0.y > 0.f ? o0.y : 0.2f * o0.y;
        o0.z = h2 * sc0.z + sh0.z; o0.z = o0.z > 0.f ? o0.z : 0.2f * o0.z;
        o0.w = h3 * sc0.w + sh0.w; o0.w = o0.w > 0.f ? o0.w : 0.2f * o0.w;
        o1.x = h4 * sc1.x + sh1.x; o1.x = o1.x > 0.f ? o1.x : 0.2f * o1.x;
        o1.y = h5 * sc1.y + sh1.y; o1.y = o1.y > 0.f ? o1.y : 0.2f * o1.y;
        o1.z = h6 * sc1.z + sh1.z; o1.z = o1.z > 0.f ? o1.z : 0.2f * o1.z;
        o1.w = h7 * sc1.w + sh1.w; o1.w = o1.w > 0.f ? o1.w : 0.2f * o1.w;
        float4* op = reinterpret_cast<float4*>(outp + (size_t)t * 8);
        op[0] = o0;
        op[1] = o1;
    }
}

extern "C" void kernel_launch(void* const* d_in, const int* in_sizes, int n_in,
                              void* d_out, int out_size, void* d_ws, size_t ws_size,
                              hipStream_t stream) {
    const float* x         = (const float*)d_in[0];
    const float* pos       = (const float*)d_in[1];
    const int*   batch     = (const int*)d_in[2];
    const float* x_skip    = (const float*)d_in[3];
    const float* pos_skip  = (const float*)d_in[4];
    const int*   batch_skip= (const int*)d_in[5];
    const float* w_att     = (const float*)d_in[6];
    const float* W1        = (const float*)d_in[7];
    const float* b1        = (const float*)d_in[8];
    const float* gamma     = (const float*)d_in[9];
    const float* beta      = (const float*)d_in[10];

    const int Nx = in_sizes[2];      // 4096
    const int Ny = in_sizes[5];      // 16384
    const int NB = 8;
    const int strips  = Ny / 16;     // 1024
    const int gblocks = strips / 8 * 4;   // 512 gemm blocks (8 strips x 4 quarters)

    char* w = (char*)d_ws;
    uint4*  Abuf     = (uint4*)w;  w += (size_t)strips * NKS * 64 * 16;   // 12.6 MB
    uint4*  Bbuf     = (uint4*)w;  w += (size_t)NKS * NNT * 64 * 16;      // 196 KB
    ushort* hb16     = (ushort*)w; w += (size_t)Ny * CO * 2;              // 8.4 MB
    float*  psum     = (float*)w;  w += (size_t)gblocks * 64 * 4;
    float*  psq      = (float*)w;  w += (size_t)gblocks * 64 * 4;
    float*  sscale   = (float*)w;  w += (size_t)512 * 4;

    float* outp = (float*)d_out;                          // [Ny][Co] f32 out
    float4* out_tail4 = (float4*)(outp + (size_t)Ny * CO);
    const float4* pos_skip4 = (const float4*)pos_skip;
    const int4*   batch4    = (const int4*)batch_skip;

    const int total8 = Ny * CO / 8;

    k_main<<<dim3(strips + 48 + 64), dim3(256), 0, stream>>>(
        pos, batch, pos_skip, batch_skip, x, x_skip, w_att, W1,
        Abuf, Bbuf, pos_skip4, batch4, out_tail4, Nx, Ny, NB);
    k_gemm<<<dim3(gblocks), dim3(512), 0, stream>>>(
        Abuf, Bbuf, b1, hb16, psum, psq);
    k_stats<<<dim3(1), dim3(1024), 0, stream>>>(
        psum, psq, gamma, beta, sscale, Ny);
    k_final<<<dim3(2048), dim3(256), 0, stream>>>(hb16, sscale, outp, total8);
}